// Round 7
// baseline (287.463 us; speedup 1.0000x reference)
//
#include <hip/hip_runtime.h>
#include <hip/hip_bf16.h>

#define Dk 128
#define Hk 256
#define Ok 64
#define BN_EPS 1e-5f

typedef __attribute__((ext_vector_type(8))) short short8;
typedef __attribute__((ext_vector_type(4))) float f32x4;

static __device__ __forceinline__ float bf2f(ushort u) {
    union { uint32_t i; float f; } c; c.i = ((uint32_t)u) << 16; return c.f;
}
static __device__ __forceinline__ ushort f2bf(float f) {
    union { float f; uint32_t u; } c; c.f = f;
    return (ushort)((c.u + 0x7fffu + ((c.u >> 16) & 1u)) >> 16);
}

// ---------------- degree / CSR build ----------------

__global__ void count_kernel(const int* __restrict__ col, int* __restrict__ cnt, int E) {
    int e = blockIdx.x * blockDim.x + threadIdx.x;
    if (e < E) atomicAdd(&cnt[col[e]], 1);
}

__global__ void dinv_bsum_kernel(const int* __restrict__ cnt, float* __restrict__ dinv,
                                 int* __restrict__ fillc, int* __restrict__ bsum, int n) {
    __shared__ int sm[256];
    int i = blockIdx.x * 256 + threadIdx.x;
    int c = (i < n) ? cnt[i] : 0;
    if (i < n) { dinv[i] = rsqrtf((float)c + 1.0f); fillc[i] = 0; }
    sm[threadIdx.x] = c;
    __syncthreads();
    for (int s = 128; s; s >>= 1) {
        if (threadIdx.x < s) sm[threadIdx.x] += sm[threadIdx.x + s];
        __syncthreads();
    }
    if (!threadIdx.x) bsum[blockIdx.x] = sm[0];
}

__global__ void scan_base_kernel(int* __restrict__ bsum, int nb) {
    __shared__ int sm[256];
    int t = threadIdx.x;
    int carry = 0;
    for (int base = 0; base < nb; base += 256) {
        int i = base + t;
        int v = (i < nb) ? bsum[i] : 0;
        sm[t] = v;
        __syncthreads();
        for (int s = 1; s < 256; s <<= 1) {
            int add = (t >= s) ? sm[t - s] : 0;
            __syncthreads();
            sm[t] += add;
            __syncthreads();
        }
        if (i < nb) bsum[i] = carry + sm[t] - v;  // exclusive
        int tot = sm[255];
        __syncthreads();
        carry += tot;
    }
}

__global__ void scan_final_kernel(const int* __restrict__ cnt, const int* __restrict__ bbase,
                                  int* __restrict__ offv, int n) {
    __shared__ int sm[256];
    int t = threadIdx.x, i = blockIdx.x * 256 + t;
    int v = (i < n) ? cnt[i] : 0;
    sm[t] = v;
    __syncthreads();
    for (int s = 1; s < 256; s <<= 1) {
        int add = (t >= s) ? sm[t - s] : 0;
        __syncthreads();
        sm[t] += add;
        __syncthreads();
    }
    if (i < n) offv[i + 1] = bbase[blockIdx.x] + sm[t];
    if (i == 0) offv[0] = 0;
}

__global__ void fill_kernel(const int* __restrict__ row, const int* __restrict__ col,
                            const int* __restrict__ off, int* __restrict__ fillc,
                            const float* __restrict__ dinv, int2* __restrict__ ep, int E) {
    int e = blockIdx.x * blockDim.x + threadIdx.x;
    if (e < E) {
        int c = col[e], r = row[e];
        int p = atomicAdd(&fillc[c], 1);
        ep[off[c] + p] = make_int2(r, __float_as_int(dinv[r]));
    }
}

// ---------------- fused conversions: emb gather+cvt | W1/W2/W3 transpose-cvt | statsP zero ----------------

#define W1SZ (Dk * Hk)
#define W2SZ (Hk * Hk)
#define W3SZ (Hk * Ok)
#define WBLK ((W1SZ + W2SZ + W3SZ) / 256)
#define STATSP_FLOATS (2 * 64 * 512)

__global__ void cvt_all_kernel(const float* __restrict__ emb, const int* __restrict__ xidx,
                               ushort* __restrict__ embb,
                               const float* __restrict__ W1, const float* __restrict__ W2,
                               const float* __restrict__ W3, ushort* __restrict__ W1t,
                               ushort* __restrict__ W2t, ushort* __restrict__ W3t,
                               float* __restrict__ statsP, int n) {
    const int embBlocks = (n * (Dk / 8) + 255) >> 8;
    int bid = blockIdx.x;
    if (bid < embBlocks) {
        int gid = bid * 256 + threadIdx.x;
        int total = n * (Dk / 8);
        if (gid >= total) return;
        int node = gid >> 4, seg = gid & 15;
        int src = xidx[node];
        const float* p = &emb[(size_t)src * Dk + seg * 8];
        float4 lo = *(const float4*)p, hi = *(const float4*)(p + 4);
        ushort r[8] = {f2bf(lo.x), f2bf(lo.y), f2bf(lo.z), f2bf(lo.w),
                       f2bf(hi.x), f2bf(hi.y), f2bf(hi.z), f2bf(hi.w)};
        *(short8*)&embb[(size_t)gid * 8] = *(short8*)r;
        return;
    }
    bid -= embBlocks;
    if (bid < WBLK) {
        int gid = bid * 256 + threadIdx.x;
        if (gid < W1SZ) {
            int c = gid / Dk, k = gid - c * Dk;
            W1t[gid] = f2bf(W1[(size_t)k * Hk + c]);
        } else if (gid < W1SZ + W2SZ) {
            int idx = gid - W1SZ;
            int c = idx / Hk, k = idx - c * Hk;
            W2t[idx] = f2bf(W2[(size_t)k * Hk + c]);
        } else {
            int idx = gid - W1SZ - W2SZ;
            int c = idx / Hk, k = idx - c * Hk;
            W3t[idx] = f2bf(W3[(size_t)k * Ok + c]);
        }
        return;
    }
    bid -= WBLK;
    int idx = bid * 1024 + threadIdx.x * 4;
    if (idx < STATSP_FLOATS)
        *(float4*)&statsP[idx] = make_float4(0.f, 0.f, 0.f, 0.f);
}

// reduce 64-slice partials -> sc/sh
__global__ void bn_finalize_kernel(const float* __restrict__ statsP, const float* __restrict__ g,
                                   const float* __restrict__ be, float* __restrict__ ss,
                                   float invn) {
    int f = threadIdx.x;  // 256
    float sum = 0.f, sq = 0.f;
    for (int s = 0; s < 64; ++s) {
        sum += statsP[s * 512 + f];
        sq  += statsP[s * 512 + 256 + f];
    }
    float mean = sum * invn;
    float var = sq * invn - mean * mean;
    float sc = g[f] * rsqrtf(var + BN_EPS);
    ss[f] = sc;
    ss[256 + f] = fmaf(-mean, sc, be[f]);
}

// ---------------- 128-tile MFMA GEMM, double-buffered 2-phase ----------------

template<int KD, int BNT, bool STATS, bool BIAS, bool BN_A>
__global__ __launch_bounds__(256) void gemm128(
    const ushort* __restrict__ A, const ushort* __restrict__ Wt,
    ushort* __restrict__ Cout, int n, int Hout,
    const float* __restrict__ bias, float* __restrict__ statsP,
    const float* __restrict__ ss)
{
    constexpr int WN = (BNT == 128) ? 2 : 1;
    constexpr int MR = (BNT == 128) ? 4 : 2;
    constexpr int NR = 4;
    constexpr int TILE = (128 + BNT) * 32;
    constexpr int NT = KD / 32;
    __shared__ ushort lds[2 * TILE];
    __shared__ float ssc[BN_A ? KD : 1];
    __shared__ float ssh[BN_A ? KD : 1];

    const int tid = threadIdx.x;
    const int lane = tid & 63, wid = tid >> 6;
    const int wr = wid / WN, wc = wid % WN;
    const int lr = lane & 15, lg = lane >> 4;
    const int bm = blockIdx.x * 128;
    const int bn = blockIdx.y * BNT;

    if (BN_A) {
        for (int f = tid; f < KD; f += 256) {
            ssc[f] = ss[f];
            ssh[f] = ss[KD + f];
        }
        __syncthreads();
    }

    auto stage = [&](int buf, int k0) {
        ushort* As = lds + buf * TILE;
        ushort* Bs = As + 128 * 32;
        #pragma unroll
        for (int c = 0; c < 2; ++c) {
            int boff = wid * 2048 + c * 1024 + lane * 16;
            int row = boff >> 6;
            int k8 = (boff >> 4) & 3;
            int grow = bm + row; if (grow >= n) grow = n - 1;
            const ushort* src = &A[(size_t)grow * KD + k0 + k8 * 8];
            if (BN_A) {
                short8 av = *(const short8*)src;
                ushort r[8];
                #pragma unroll
                for (int j = 0; j < 8; ++j) {
                    int kf = k0 + k8 * 8 + j;
                    float v = bf2f((ushort)av[j]);
                    r[j] = f2bf(fmaxf(fmaf(v, ssc[kf], ssh[kf]), 0.f));
                }
                *(short8*)&As[row * 32 + k8 * 8] = *(short8*)r;
            } else {
                __builtin_amdgcn_global_load_lds(
                    (const __attribute__((address_space(1))) void*)src,
                    (__attribute__((address_space(3))) void*)&As[(wid * 2048 + c * 1024) >> 1],
                    16, 0, 0);
            }
        }
        constexpr int BC = BNT * 64 / 4096;
        #pragma unroll
        for (int c = 0; c < BC; ++c) {
            int boff = wid * (BNT * 16) + c * 1024 + lane * 16;
            int col = boff >> 6;
            int k8 = (boff >> 4) & 3;
            const ushort* src = &Wt[(size_t)(bn + col) * KD + k0 + k8 * 8];
            __builtin_amdgcn_global_load_lds(
                (const __attribute__((address_space(1))) void*)src,
                (__attribute__((address_space(3))) void*)&Bs[(wid * (BNT * 16) + c * 1024) >> 1],
                16, 0, 0);
        }
    };

    f32x4 acc[MR][NR] = {};

    stage(0, 0);
    __syncthreads();
    int cur = 0;
    for (int t = 0; t < NT; ++t) {
        if (t + 1 < NT) stage(cur ^ 1, (t + 1) * 32);
        ushort* As = lds + cur * TILE;
        ushort* Bs = As + 128 * 32;
        short8 af[MR], bfr[NR];
        #pragma unroll
        for (int m = 0; m < MR; ++m)
            af[m] = *(const short8*)&As[(wr * MR * 16 + m * 16 + lr) * 32 + lg * 8];
        #pragma unroll
        for (int nn = 0; nn < NR; ++nn)
            bfr[nn] = *(const short8*)&Bs[(wc * NR * 16 + nn * 16 + lr) * 32 + lg * 8];
        #pragma unroll
        for (int m = 0; m < MR; ++m)
            #pragma unroll
            for (int nn = 0; nn < NR; ++nn)
                acc[m][nn] = __builtin_amdgcn_mfma_f32_16x16x32_bf16(af[m], bfr[nn], acc[m][nn], 0, 0, 0);
        __syncthreads();
        cur ^= 1;
    }

    float s[NR], q[NR];
    #pragma unroll
    for (int nn = 0; nn < NR; ++nn) { s[nn] = 0.f; q[nn] = 0.f; }
    #pragma unroll
    for (int nn = 0; nn < NR; ++nn) {
        int col = bn + wc * NR * 16 + nn * 16 + lr;
        float bv = BIAS ? bias[col] : 0.f;
        #pragma unroll
        for (int m = 0; m < MR; ++m) {
            #pragma unroll
            for (int i = 0; i < 4; ++i) {
                int row = bm + wr * MR * 16 + m * 16 + lg * 4 + i;
                if (row < n) {
                    float v = acc[m][nn][i] + bv;
                    Cout[(size_t)row * Hout + col] = f2bf(v);
                    if (STATS) { s[nn] += v; q[nn] += v * v; }
                }
            }
        }
    }
    if (STATS) {
        float* sp = statsP + (size_t)(blockIdx.x & 63) * 512;
        #pragma unroll
        for (int nn = 0; nn < NR; ++nn) {
            s[nn] += __shfl_xor(s[nn], 16);
            q[nn] += __shfl_xor(q[nn], 16);
            s[nn] += __shfl_xor(s[nn], 32);
            q[nn] += __shfl_xor(q[nn], 32);
            if (lg == 0) {
                int col = bn + wc * NR * 16 + nn * 16 + lr;
                atomicAdd(&sp[col], s[nn]);
                atomicAdd(&sp[256 + col], q[nn]);
            }
        }
    }
}

// ---------------- CSR-pull aggregation: LPN lanes/node, VEC=4 (8B loads), 8 edges in flight ----------------
// MODE 0: plain -> bf16    MODE 1: relu(sc*x+sh) per gathered elem -> bf16
// MODE 2: + bias -> f32

template<int FH, int LPN, int MODE>
__global__ __launch_bounds__(256) void agg_kernel(
    const ushort* __restrict__ x, const int2* __restrict__ ep, const int* __restrict__ off,
    const float* __restrict__ dinv, const float* __restrict__ ss,
    const float* __restrict__ bias, void* __restrict__ outp, int n)
{
    constexpr int VEC = FH / LPN;        // 4 for all instantiations
    constexpr int NPW = 64 / LPN;        // nodes per wave
    constexpr int NPB = 4 * NPW;         // nodes per block
    const int tid = threadIdx.x;
    const int lane = tid & 63;
    const int wid = tid >> 6;
    const int sub = lane / LPN;
    const int flane = lane % LPN;
    const int node = blockIdx.x * NPB + wid * NPW + sub;
    if (node >= n) return;
    const int fb = flane * VEC;
    const ushort* __restrict__ xb = x + fb;

    float sc[VEC], sh[VEC];
    if (MODE == 1) {
        float4 c4 = *(const float4*)&ss[fb];
        float4 h4 = *(const float4*)&ss[FH + fb];
        sc[0] = c4.x; sc[1] = c4.y; sc[2] = c4.z; sc[3] = c4.w;
        sh[0] = h4.x; sh[1] = h4.y; sh[2] = h4.z; sh[3] = h4.w;
    }
    auto xform = [&](ushort u, int v) -> float {
        float val = bf2f(u);
        if (MODE == 1) val = fmaxf(fmaf(val, sc[v], sh[v]), 0.f);
        return val;
    };

    float di = dinv[node];
    float acc[VEC];
    {
        ushort4 t = *(const ushort4*)&xb[(size_t)node * FH];
        acc[0] = di * xform(t.x, 0); acc[1] = di * xform(t.y, 1);
        acc[2] = di * xform(t.z, 2); acc[3] = di * xform(t.w, 3);
    }
    const int e1 = off[node + 1];
    int e = off[node];
    for (; e + 8 <= e1; e += 8) {
        int2 p[8];
        ushort4 t[8];
        #pragma unroll
        for (int j = 0; j < 8; ++j) p[j] = ep[e + j];
        #pragma unroll
        for (int j = 0; j < 8; ++j) t[j] = *(const ushort4*)&xb[(size_t)p[j].x * FH];
        #pragma unroll
        for (int j = 0; j < 8; ++j) {
            float w = __int_as_float(p[j].y);
            acc[0] = fmaf(w, xform(t[j].x, 0), acc[0]);
            acc[1] = fmaf(w, xform(t[j].y, 1), acc[1]);
            acc[2] = fmaf(w, xform(t[j].z, 2), acc[2]);
            acc[3] = fmaf(w, xform(t[j].w, 3), acc[3]);
        }
    }
    for (; e + 2 <= e1; e += 2) {
        int2 p0 = ep[e], p1 = ep[e + 1];
        ushort4 t0 = *(const ushort4*)&xb[(size_t)p0.x * FH];
        ushort4 t1 = *(const ushort4*)&xb[(size_t)p1.x * FH];
        float w0 = __int_as_float(p0.y), w1 = __int_as_float(p1.y);
        acc[0] = fmaf(w0, xform(t0.x, 0), acc[0]); acc[1] = fmaf(w0, xform(t0.y, 1), acc[1]);
        acc[2] = fmaf(w0, xform(t0.z, 2), acc[2]); acc[3] = fmaf(w0, xform(t0.w, 3), acc[3]);
        acc[0] = fmaf(w1, xform(t1.x, 0), acc[0]); acc[1] = fmaf(w1, xform(t1.y, 1), acc[1]);
        acc[2] = fmaf(w1, xform(t1.z, 2), acc[2]); acc[3] = fmaf(w1, xform(t1.w, 3), acc[3]);
    }
    if (e < e1) {
        int2 pp = ep[e];
        ushort4 tt = *(const ushort4*)&xb[(size_t)pp.x * FH];
        float w = __int_as_float(pp.y);
        acc[0] = fmaf(w, xform(tt.x, 0), acc[0]); acc[1] = fmaf(w, xform(tt.y, 1), acc[1]);
        acc[2] = fmaf(w, xform(tt.z, 2), acc[2]); acc[3] = fmaf(w, xform(tt.w, 3), acc[3]);
    }
    if (MODE == 2) {
        float4 bv = *(const float4*)&bias[fb];
        float4 res;
        res.x = fmaf(di, acc[0], bv.x); res.y = fmaf(di, acc[1], bv.y);
        res.z = fmaf(di, acc[2], bv.z); res.w = fmaf(di, acc[3], bv.w);
        *(float4*)((float*)outp + (size_t)node * FH + fb) = res;
    } else {
        ushort4 o;
        o.x = f2bf(di * acc[0]); o.y = f2bf(di * acc[1]);
        o.z = f2bf(di * acc[2]); o.w = f2bf(di * acc[3]);
        *(ushort4*)((ushort*)outp + (size_t)node * FH + fb) = o;
    }
}

// ---------------- host launch ----------------

extern "C" void kernel_launch(void* const* d_in, const int* in_sizes, int n_in,
                              void* d_out, int out_size, void* d_ws, size_t ws_size,
                              hipStream_t stream) {
    const int*   x_idx = (const int*)d_in[0];
    const int*   ei    = (const int*)d_in[1];
    const float* emb   = (const float*)d_in[2];
    const float* W1    = (const float*)d_in[3];
    const float* b1    = (const float*)d_in[4];
    const float* g1    = (const float*)d_in[5];
    const float* be1   = (const float*)d_in[6];
    const float* W2    = (const float*)d_in[7];
    const float* b2    = (const float*)d_in[8];
    const float* g2    = (const float*)d_in[9];
    const float* be2   = (const float*)d_in[10];
    const float* W3    = (const float*)d_in[11];
    const float* b3    = (const float*)d_in[12];

    const int N = in_sizes[0];
    const int E = in_sizes[1] / 2;
    const int* erow = ei;       // source
    const int* ecol = ei + E;   // target

    char* p = (char*)d_ws;
    auto alloc = [&](size_t bytes) { char* q = p; p += (bytes + 255) & ~(size_t)255; return q; };
    const int nb = (N + 255) / 256;
    float*  dinv  = (float*) alloc((size_t)N * 4);
    int*    cnt   = (int*)   alloc((size_t)N * 4);
    int*    off   = (int*)   alloc((size_t)(N + 1) * 4);
    int*    fillc = (int*)   alloc((size_t)N * 4);
    int*    bsum  = (int*)   alloc((size_t)nb * 4);
    int2*   ep    = (int2*)  alloc((size_t)E * 8);
    float*  statsP= (float*) alloc((size_t)STATSP_FLOATS * 4);
    float*  stats1P = statsP, *stats2P = statsP + 64 * 512;
    float*  ss1   = (float*) alloc(512 * 4);
    float*  ss2   = (float*) alloc(512 * 4);
    ushort* W1t   = (ushort*)alloc((size_t)Dk * Hk * 2);   // [Hk][Dk]
    ushort* W2t   = (ushort*)alloc((size_t)Hk * Hk * 2);   // [Hk][Hk]
    ushort* W3t   = (ushort*)alloc((size_t)Hk * Ok * 2);   // [Ok][Hk]
    ushort* bufU  = (ushort*)alloc((size_t)N * Hk * 2);    // embb+agg1b, later conv2
    ushort* embb  = bufU;
    ushort* agg1b = bufU + (size_t)N * Dk;
    ushort* conv2b= bufU;
    ushort* conv1b= (ushort*)alloc((size_t)N * Hk * 2);
    ushort* agg2b = (ushort*)alloc((size_t)N * Hk * 2);
    ushort* xl3b  = (ushort*)alloc((size_t)N * Ok * 2);

    const float invn = 1.0f / (float)N;

    // --- graph preprocessing ---
    hipMemsetAsync(cnt, 0, (size_t)N * 4, stream);
    count_kernel<<<(E + 255) / 256, 256, 0, stream>>>(ecol, cnt, E);
    dinv_bsum_kernel<<<nb, 256, 0, stream>>>(cnt, dinv, fillc, bsum, N);
    scan_base_kernel<<<1, 256, 0, stream>>>(bsum, nb);
    scan_final_kernel<<<nb, 256, 0, stream>>>(cnt, bsum, off, N);
    fill_kernel<<<(E + 255) / 256, 256, 0, stream>>>(erow, ecol, off, fillc, dinv, ep, E);

    // --- fused conversions + statsP zero ---
    const int embBlocks = (N * (Dk / 8) + 255) / 256;
    cvt_all_kernel<<<embBlocks + WBLK + (STATSP_FLOATS + 1023) / 1024, 256, 0, stream>>>(
        emb, x_idx, embb, W1, W2, W3, W1t, W2t, W3t, statsP, N);

    const int rb128 = (N + 127) / 128;

    // --- layer 1: agg(emb) @ W1 + b1 -> conv1 (stats1 fused) ---
    agg_kernel<Dk, 32, 0><<<(N + 7) / 8, 256, 0, stream>>>(
        embb, ep, off, dinv, nullptr, nullptr, agg1b, N);
    gemm128<Dk, 128, true, true, false><<<dim3(rb128, Hk / 128), 256, 0, stream>>>(
        agg1b, W1t, conv1b, N, Hk, b1, stats1P, nullptr);
    bn_finalize_kernel<<<1, 256, 0, stream>>>(stats1P, g1, be1, ss1, invn);

    // --- layer 2: agg(relu(bn(conv1))) @ W2 + b2 -> conv2 ---
    agg_kernel<Hk, 64, 1><<<(N + 3) / 4, 256, 0, stream>>>(
        conv1b, ep, off, dinv, ss1, nullptr, agg2b, N);
    gemm128<Hk, 128, true, true, false><<<dim3(rb128, Hk / 128), 256, 0, stream>>>(
        agg2b, W2t, conv2b, N, Hk, b2, stats2P, nullptr);
    bn_finalize_kernel<<<1, 256, 0, stream>>>(stats2P, g2, be2, ss2, invn);

    // --- layer 3: (relu(bn(conv2)) @ W3) aggregated + b3 -> d_out ---
    gemm128<Hk, 64, false, false, true><<<dim3(rb128, 1), 256, 0, stream>>>(
        conv2b, W3t, xl3b, N, Ok, nullptr, nullptr, ss2);
    agg_kernel<Ok, 16, 2><<<(N + 15) / 16, 256, 0, stream>>>(
        xl3b, ep, off, dinv, nullptr, b3, d_out, N);
}